// Round 2
// baseline (196.254 us; speedup 1.0000x reference)
//
#include <hip/hip_runtime.h>
#include <hip/hip_bf16.h>
#include <stdint.h>

typedef __bf16 bf16;
typedef __bf16 bf16x8 __attribute__((ext_vector_type(8)));
typedef __bf16 bf16x4 __attribute__((ext_vector_type(4)));
typedef float  f32x4  __attribute__((ext_vector_type(4)));

#define DM 1024
#define NH 16
#define HD 64
#define TT 2048

// log2(e)/8 : puts QK^T scores directly in exp2 domain
#define QSCALE 0.18033688011112042f

// one fused fp32->bf16 convert over x + 4 weights (saves 4 launches)
__global__ void cvt_all(const float* __restrict__ x,  const float* __restrict__ wq,
                        const float* __restrict__ wk, const float* __restrict__ wv,
                        const float* __restrict__ wo,
                        bf16* __restrict__ xb,  bf16* __restrict__ wqb,
                        bf16* __restrict__ wkb, bf16* __restrict__ wvb,
                        bf16* __restrict__ wob) {
  const int i = (blockIdx.x * blockDim.x + threadIdx.x) * 4;
  const float* src; bf16* dst; int off;
  if (i < 4194304)      { src = x;  dst = xb;  off = i; }
  else {
    const int j = i - 4194304;
    const int w = j >> 20;            // which weight
    off = j & 1048575;
    src = (w == 0) ? wq : (w == 1) ? wk : (w == 2) ? wv : wo;
    dst = (w == 0) ? wqb : (w == 1) ? wkb : (w == 2) ? wvb : wob;
  }
  const float4 v = *reinterpret_cast<const float4*>(src + off);
  bf16x4 o = { (bf16)v.x, (bf16)v.y, (bf16)v.z, (bf16)v.w };
  *reinterpret_cast<bf16x4*>(dst + off) = o;
}

static __device__ __forceinline__ void gload_lds16(const bf16* g, bf16* l) {
  __builtin_amdgcn_global_load_lds(
      (__attribute__((address_space(1))) void*)g,
      (__attribute__((address_space(3))) void*)l, 16, 0, 0);
}

// C = X @ W^T for 3 weight matrices; scatter epilogue into attention layouts.
// Qb/Kb: [32 bh][2048 t][64 d]; Vtb: [32 bh][64 d][2048 t]. Q pre-scaled QSCALE.
__launch_bounds__(256, 2)
__global__ void gemm_qkv(const bf16* __restrict__ X, const bf16* __restrict__ Wq,
                         const bf16* __restrict__ Wk, const bf16* __restrict__ Wv,
                         bf16* __restrict__ Qb, bf16* __restrict__ Kb,
                         bf16* __restrict__ Vtb) {
  __shared__ bf16 As[128 * 32];
  __shared__ bf16 Bs[128 * 32];
  const int tid  = threadIdx.x;
  const int lane = tid & 63;
  const int wv   = tid >> 6;
  const int lg   = lane >> 4, lc = lane & 15;
  const int m0   = blockIdx.x * 128;
  const int ng   = blockIdx.y * 128;
  const int which = ng >> 10;                 // 0=Q 1=K 2=V
  const bf16* W = (which == 0) ? Wq : ((which == 1) ? Wk : Wv);
  const int n0 = ng & 1023;
  const int wm = wv >> 1, wn = wv & 1;

  f32x4 acc[4][4] = {};

  for (int k0 = 0; k0 < DM; k0 += 32) {
#pragma unroll
    for (int c = 0; c < 2; ++c) {
      const int e   = wv * 512 + c * 2048 + lane * 8;
      const int row = e >> 5, col = e & 31;
      gload_lds16(X + (size_t)(m0 + row) * DM + k0 + col, &As[wv * 512 + c * 2048]);
      gload_lds16(W + (size_t)(n0 + row) * DM + k0 + col, &Bs[wv * 512 + c * 2048]);
    }
    __syncthreads();
    bf16x8 a[4], b[4];
#pragma unroll
    for (int i = 0; i < 4; ++i)
      a[i] = *reinterpret_cast<const bf16x8*>(&As[(wm * 64 + i * 16 + lc) * 32 + lg * 8]);
#pragma unroll
    for (int j = 0; j < 4; ++j)
      b[j] = *reinterpret_cast<const bf16x8*>(&Bs[(wn * 64 + j * 16 + lc) * 32 + lg * 8]);
#pragma unroll
    for (int i = 0; i < 4; ++i)
#pragma unroll
      for (int j = 0; j < 4; ++j)
        acc[i][j] = __builtin_amdgcn_mfma_f32_16x16x32_bf16(a[i], b[j], acc[i][j], 0, 0, 0);
    __syncthreads();
  }

#pragma unroll
  for (int i = 0; i < 4; ++i) {
    const int mg = m0 + wm * 64 + i * 16 + lg * 4;
    const int bb = mg >> 11, t = mg & 2047;
#pragma unroll
    for (int j = 0; j < 4; ++j) {
      const int nl = n0 + wn * 64 + j * 16 + lc;
      const int h = nl >> 6, d = nl & 63;
      const int bh = bb * NH + h;
      const f32x4 v = acc[i][j];
      if (which == 0) {
        bf16* p = Qb + ((size_t)bh * TT + t) * HD + d;
#pragma unroll
        for (int r = 0; r < 4; ++r) p[r * HD] = (bf16)(v[r] * QSCALE);
      } else if (which == 1) {
        bf16* p = Kb + ((size_t)bh * TT + t) * HD + d;
#pragma unroll
        for (int r = 0; r < 4; ++r) p[r * HD] = (bf16)v[r];
      } else {
        bf16x4 pk = { (bf16)v[0], (bf16)v[1], (bf16)v[2], (bf16)v[3] };
        *reinterpret_cast<bf16x4*>(Vtb + ((size_t)bh * HD + d) * TT + t) = pk;
      }
    }
  }
}

#define KVB 64
#define KPAD 72

// Wave-independent flash attention. No barriers. K/V fragments direct from
// global (L2-resident). Swapped QK^T: s[j] = mfma(K, Q) -> lane holds
// S^T[kv = j*16+lg*4+r][q = lc]: softmax is in-lane + 2 shfl_xor rounds.
__launch_bounds__(256, 4)
__global__ void attn_fwd(const bf16* __restrict__ Qb, const bf16* __restrict__ Kb,
                         const bf16* __restrict__ Vtb, bf16* __restrict__ Yb) {
  __shared__ bf16 Ps[4 * 16 * KPAD];   // per-wave P [16 q][64 kv] (+pad)

  const int tid  = threadIdx.x;
  const int lane = tid & 63;
  const int wv   = tid >> 6;
  const int lg   = lane >> 4;
  const int lc   = lane & 15;
  const int bh   = blockIdx.x & 31;
  const int g    = blockIdx.x >> 5;    // 0..31
  // balance: per-256-block round qblks sum ~constant per CU
  const int qblk = (g < 8) ? (31 - g) : (g < 16) ? (g - 8)
                 : (g < 24) ? (39 - g) : (g - 16);
  const int q0 = qblk * 64;
  const int qw = q0 + wv * 16;

  const bf16* Qg = Qb  + (size_t)bh * TT * HD;
  const bf16* Kg = Kb  + (size_t)bh * TT * HD;
  const bf16* Vg = Vtb + (size_t)bh * HD * TT;

  // Q fragments (B-operand) in registers, pre-scaled by QSCALE
  bf16x8 qf[2];
#pragma unroll
  for (int ks = 0; ks < 2; ++ks)
    qf[ks] = *reinterpret_cast<const bf16x8*>(Qg + (size_t)(qw + lc) * HD + ks * 32 + lg * 8);

  f32x4 o[4] = {};
  float m_run = -INFINITY, l_run = 0.f;   // stats for q-row (qw + lc)
  bf16* Pw = &Ps[wv * 16 * KPAD];

  const int ntiles = qblk + 1;
  for (int ti = 0; ti < ntiles; ++ti) {
    const int k0 = ti * KVB;
    const bf16* Kt = Kg + (size_t)k0 * HD;

    // S^T = K Q^T : lane holds s[j][r] = S[kv = k0+j*16+lg*4+r][q = qw+lc]
    f32x4 s[4];
#pragma unroll
    for (int j = 0; j < 4; ++j) {
      f32x4 z = {};
#pragma unroll
      for (int ks = 0; ks < 2; ++ks) {
        const bf16x8 kf = *reinterpret_cast<const bf16x8*>(
            Kt + (size_t)(j * 16 + lc) * HD + ks * 32 + lg * 8);
        z = __builtin_amdgcn_mfma_f32_16x16x32_bf16(kf, qf[ks], z, 0, 0, 0);
      }
      s[j] = z;
    }

    // causal mask on the diagonal tile
    if (k0 == q0) {
      const int q = qw + lc;
#pragma unroll
      for (int j = 0; j < 4; ++j)
#pragma unroll
        for (int r = 0; r < 4; ++r)
          if (k0 + j * 16 + lg * 4 + r > q) s[j][r] = -INFINITY;
    }

    // online softmax (exp2 domain), row = q = lc
    float rmax = -INFINITY;
#pragma unroll
    for (int j = 0; j < 4; ++j)
#pragma unroll
      for (int r = 0; r < 4; ++r) rmax = fmaxf(rmax, s[j][r]);
    rmax = fmaxf(rmax, __shfl_xor(rmax, 16));
    rmax = fmaxf(rmax, __shfl_xor(rmax, 32));

    const float mn = fmaxf(m_run, rmax);
    const float alpha = exp2f(m_run - mn);   // first tile: exp2(-inf)=0
    m_run = mn;

    float rsum = 0.f;
#pragma unroll
    for (int j = 0; j < 4; ++j)
#pragma unroll
      for (int r = 0; r < 4; ++r) {
        const float p = exp2f(s[j][r] - mn);
        s[j][r] = p;
        rsum += p;
      }
    rsum += __shfl_xor(rsum, 16);
    rsum += __shfl_xor(rsum, 32);
    l_run = l_run * alpha + rsum;

    // redistribute alpha from stat layout (q=lc) to acc layout (q=lg*4+r)
    float ar[4];
#pragma unroll
    for (int r = 0; r < 4; ++r) ar[r] = __shfl(alpha, lg * 4 + r);
#pragma unroll
    for (int df = 0; df < 4; ++df)
#pragma unroll
      for (int r = 0; r < 4; ++r) o[df][r] *= ar[r];

    // P pack: lane writes 4 consecutive kv for q=lc -> b64 stores
#pragma unroll
    for (int j = 0; j < 4; ++j) {
      bf16x4 pk = { (bf16)s[j][0], (bf16)s[j][1], (bf16)s[j][2], (bf16)s[j][3] };
      *reinterpret_cast<bf16x4*>(&Pw[lc * KPAD + j * 16 + lg * 4]) = pk;
    }

    // O += P V : P as A-operand re-read from LDS; V direct from global
#pragma unroll
    for (int ks = 0; ks < 2; ++ks) {
      const bf16x8 pf = *reinterpret_cast<const bf16x8*>(&Pw[lc * KPAD + ks * 32 + lg * 8]);
#pragma unroll
      for (int df = 0; df < 4; ++df) {
        const bf16x8 vf = *reinterpret_cast<const bf16x8*>(
            Vg + (size_t)(df * 16 + lc) * TT + k0 + ks * 32 + lg * 8);
        o[df] = __builtin_amdgcn_mfma_f32_16x16x32_bf16(pf, vf, o[df], 0, 0, 0);
      }
    }
  }

  // normalize + write y[b*T + t][h*64 + d]
  const int b = bh >> 4, h = bh & 15;
  const float linv = 1.f / fmaxf(l_run, 1e-9f);
  float ir[4];
#pragma unroll
  for (int r = 0; r < 4; ++r) ir[r] = __shfl(linv, lg * 4 + r);
#pragma unroll
  for (int df = 0; df < 4; ++df)
#pragma unroll
    for (int r = 0; r < 4; ++r) {
      const int q = qw + lg * 4 + r;
      Yb[((size_t)(b * TT + q)) * DM + h * HD + df * 16 + lc] = (bf16)(o[df][r] * ir[r]);
    }
}

// Out = Y @ Wo^T, fp32 output row-major [4096,1024]
__launch_bounds__(256, 2)
__global__ void gemm_out(const bf16* __restrict__ Y, const bf16* __restrict__ Wo,
                         float* __restrict__ Out) {
  __shared__ bf16 As[128 * 32];
  __shared__ bf16 Bs[128 * 32];
  const int tid  = threadIdx.x;
  const int lane = tid & 63;
  const int wv   = tid >> 6;
  const int lg   = lane >> 4, lc = lane & 15;
  const int m0   = blockIdx.x * 128;
  const int n0   = blockIdx.y * 128;
  const int wm = wv >> 1, wn = wv & 1;

  f32x4 acc[4][4] = {};

  for (int k0 = 0; k0 < DM; k0 += 32) {
#pragma unroll
    for (int c = 0; c < 2; ++c) {
      const int e   = wv * 512 + c * 2048 + lane * 8;
      const int row = e >> 5, col = e & 31;
      gload_lds16(Y  + (size_t)(m0 + row) * DM + k0 + col, &As[wv * 512 + c * 2048]);
      gload_lds16(Wo + (size_t)(n0 + row) * DM + k0 + col, &Bs[wv * 512 + c * 2048]);
    }
    __syncthreads();
    bf16x8 a[4], b[4];
#pragma unroll
    for (int i = 0; i < 4; ++i)
      a[i] = *reinterpret_cast<const bf16x8*>(&As[(wm * 64 + i * 16 + lc) * 32 + lg * 8]);
#pragma unroll
    for (int j = 0; j < 4; ++j)
      b[j] = *reinterpret_cast<const bf16x8*>(&Bs[(wn * 64 + j * 16 + lc) * 32 + lg * 8]);
#pragma unroll
    for (int i = 0; i < 4; ++i)
#pragma unroll
      for (int j = 0; j < 4; ++j)
        acc[i][j] = __builtin_amdgcn_mfma_f32_16x16x32_bf16(a[i], b[j], acc[i][j], 0, 0, 0);
    __syncthreads();
  }

#pragma unroll
  for (int i = 0; i < 4; ++i) {
    const int mg = m0 + wm * 64 + i * 16 + lg * 4;
#pragma unroll
    for (int j = 0; j < 4; ++j) {
      const int n = n0 + wn * 64 + j * 16 + lc;
#pragma unroll
      for (int r = 0; r < 4; ++r)
        Out[(size_t)(mg + r) * DM + n] = acc[i][j][r];
    }
  }
}

extern "C" void kernel_launch(void* const* d_in, const int* in_sizes, int n_in,
                              void* d_out, int out_size, void* d_ws, size_t ws_size,
                              hipStream_t stream) {
  const float* x  = (const float*)d_in[0];
  const float* Wq = (const float*)d_in[1];
  const float* Wk = (const float*)d_in[2];
  const float* Wv = (const float*)d_in[3];
  const float* Wo = (const float*)d_in[4];
  float* out = (float*)d_out;
  char* ws = (char*)d_ws;
  const size_t MB = 1024 * 1024;

  bf16* xb  = (bf16*)(ws + 0);        // 8 MB, reused as yb after QKV GEMM
  bf16* wqb = (bf16*)(ws + 8  * MB);
  bf16* wkb = (bf16*)(ws + 10 * MB);
  bf16* wvb = (bf16*)(ws + 12 * MB);
  bf16* wob = (bf16*)(ws + 14 * MB);
  bf16* Qb  = (bf16*)(ws + 16 * MB);  // [32,2048,64]
  bf16* Kb  = (bf16*)(ws + 24 * MB);
  bf16* Vtb = (bf16*)(ws + 32 * MB);  // [32,64,2048]
  bf16* yb  = xb;

  cvt_all<<<8192, 256, 0, stream>>>(x, Wq, Wk, Wv, Wo, xb, wqb, wkb, wvb, wob);
  gemm_qkv<<<dim3(32, 24), 256, 0, stream>>>(xb, wqb, wkb, wvb, Qb, Kb, Vtb);
  attn_fwd<<<dim3(1024), 256, 0, stream>>>(Qb, Kb, Vtb, yb);
  gemm_out<<<dim3(32, 8), 256, 0, stream>>>(yb, wob, out);
}

// Round 3
// 118.944 us; speedup vs baseline: 1.6500x; 1.6500x over previous
//
#include <hip/hip_runtime.h>
#include <hip/hip_bf16.h>
#include <stdint.h>

typedef __bf16 bf16;
typedef __bf16 bf16x8 __attribute__((ext_vector_type(8)));
typedef __bf16 bf16x4 __attribute__((ext_vector_type(4)));
typedef float  f32x4  __attribute__((ext_vector_type(4)));

#define DM 1024
#define NH 16
#define HD 64
#define TT 2048

// log2(e)/8 : puts QK^T scores directly in exp2 domain
#define QSCALE 0.18033688011112042f

__global__ void cvt_all(const float* __restrict__ x,  const float* __restrict__ wq,
                        const float* __restrict__ wk, const float* __restrict__ wv,
                        const float* __restrict__ wo,
                        bf16* __restrict__ xb,  bf16* __restrict__ wqb,
                        bf16* __restrict__ wkb, bf16* __restrict__ wvb,
                        bf16* __restrict__ wob) {
  const int i = (blockIdx.x * blockDim.x + threadIdx.x) * 4;
  const float* src; bf16* dst; int off;
  if (i < 4194304)      { src = x;  dst = xb;  off = i; }
  else {
    const int j = i - 4194304;
    const int w = j >> 20;
    off = j & 1048575;
    src = (w == 0) ? wq : (w == 1) ? wk : (w == 2) ? wv : wo;
    dst = (w == 0) ? wqb : (w == 1) ? wkb : (w == 2) ? wvb : wob;
  }
  const float4 v = *reinterpret_cast<const float4*>(src + off);
  bf16x4 o = { (bf16)v.x, (bf16)v.y, (bf16)v.z, (bf16)v.w };
  *reinterpret_cast<bf16x4*>(dst + off) = o;
}

static __device__ __forceinline__ void gload_lds16(const bf16* g, bf16* l) {
  __builtin_amdgcn_global_load_lds(
      (__attribute__((address_space(1))) void*)g,
      (__attribute__((address_space(3))) void*)l, 16, 0, 0);
}

// XOR swizzle: spreads the 8 16B-slots of a 128B row across banks by row
static __device__ __forceinline__ int swzb(int lin) {
  return lin ^ (((lin >> 7) & 7) << 4);
}

// ---------------- QKV projection (m97-style) ----------------
__launch_bounds__(256, 2)
__global__ void gemm_qkv(const bf16* __restrict__ X, const bf16* __restrict__ Wq,
                         const bf16* __restrict__ Wk, const bf16* __restrict__ Wv,
                         bf16* __restrict__ Qb, bf16* __restrict__ Kb,
                         bf16* __restrict__ Vtb) {
  __shared__ bf16 As[128 * 32];
  __shared__ bf16 Bs[128 * 32];
  const int tid  = threadIdx.x;
  const int lane = tid & 63;
  const int wv   = tid >> 6;
  const int lg   = lane >> 4, lc = lane & 15;
  const int m0   = blockIdx.x * 128;
  const int ng   = blockIdx.y * 128;
  const int which = ng >> 10;                 // 0=Q 1=K 2=V
  const bf16* W = (which == 0) ? Wq : ((which == 1) ? Wk : Wv);
  const int n0 = ng & 1023;
  const int wm = wv >> 1, wn = wv & 1;

  f32x4 acc[4][4] = {};

  for (int k0 = 0; k0 < DM; k0 += 32) {
#pragma unroll
    for (int c = 0; c < 2; ++c) {
      const int e   = wv * 512 + c * 2048 + lane * 8;
      const int row = e >> 5, col = e & 31;
      gload_lds16(X + (size_t)(m0 + row) * DM + k0 + col, &As[wv * 512 + c * 2048]);
      gload_lds16(W + (size_t)(n0 + row) * DM + k0 + col, &Bs[wv * 512 + c * 2048]);
    }
    __syncthreads();
    bf16x8 a[4], b[4];
#pragma unroll
    for (int i = 0; i < 4; ++i)
      a[i] = *reinterpret_cast<const bf16x8*>(&As[(wm * 64 + i * 16 + lc) * 32 + lg * 8]);
#pragma unroll
    for (int j = 0; j < 4; ++j)
      b[j] = *reinterpret_cast<const bf16x8*>(&Bs[(wn * 64 + j * 16 + lc) * 32 + lg * 8]);
#pragma unroll
    for (int i = 0; i < 4; ++i)
#pragma unroll
      for (int j = 0; j < 4; ++j)
        acc[i][j] = __builtin_amdgcn_mfma_f32_16x16x32_bf16(a[i], b[j], acc[i][j], 0, 0, 0);
    __syncthreads();
  }

#pragma unroll
  for (int i = 0; i < 4; ++i) {
    const int mg = m0 + wm * 64 + i * 16 + lg * 4;
    const int bb = mg >> 11, t = mg & 2047;
#pragma unroll
    for (int j = 0; j < 4; ++j) {
      const int nl = n0 + wn * 64 + j * 16 + lc;
      const int h = nl >> 6, d = nl & 63;
      const int bh = bb * NH + h;
      const f32x4 v = acc[i][j];
      if (which == 0) {
        bf16* p = Qb + ((size_t)bh * TT + t) * HD + d;
#pragma unroll
        for (int r = 0; r < 4; ++r) p[r * HD] = (bf16)(v[r] * QSCALE);
      } else if (which == 1) {
        bf16* p = Kb + ((size_t)bh * TT + t) * HD + d;
#pragma unroll
        for (int r = 0; r < 4; ++r) p[r * HD] = (bf16)v[r];
      } else {
        bf16x4 pk = { (bf16)v[0], (bf16)v[1], (bf16)v[2], (bf16)v[3] };
        *reinterpret_cast<bf16x4*>(Vtb + ((size_t)bh * HD + d) * TT + t) = pk;
      }
    }
  }
}

// ---------------- flash attention: 2-phase pipelined, swizzled LDS ----------------
// 512 blocks: bh = bid&31, g = bid>>5, qblk pairing balances co-resident blocks.
// Block covers 128 q rows; wave wv owns q = q0 + qf*64 + wv*16 + lc (qf=0,1).
__launch_bounds__(256, 2)
__global__ void attn_fwd(const bf16* __restrict__ Qb, const bf16* __restrict__ Kb,
                         const bf16* __restrict__ Vtb, bf16* __restrict__ Yb) {
  __shared__ bf16 Ks[2][4096];    // [buf][64 kv x 64 d]  (swizzled rows)
  __shared__ bf16 Vs[2][4096];    // [buf][64 d x 64 kv]  (swizzled rows)
  __shared__ bf16 Ps[4][32 * 72]; // per-wave P [32 q][64 kv + pad]

  const int tid  = threadIdx.x;
  const int lane = tid & 63;
  const int wv   = tid >> 6;
  const int lg   = lane >> 4;
  const int lc   = lane & 15;
  const int bh   = blockIdx.x & 31;
  const int g    = blockIdx.x >> 5;
  const int qblk = (g < 8) ? (15 - g) : (g - 8);
  const int q0   = qblk * 128;

  const bf16* Qg = Qb  + (size_t)bh * TT * HD;
  const bf16* Kg = Kb  + (size_t)bh * TT * HD;
  const bf16* Vg = Vtb + (size_t)bh * HD * TT;

  // Q fragments (B-operand), pre-scaled by QSCALE in the QKV epilogue
  bf16x8 qreg[2][2];
#pragma unroll
  for (int qf = 0; qf < 2; ++qf)
#pragma unroll
    for (int ks = 0; ks < 2; ++ks)
      qreg[qf][ks] = *reinterpret_cast<const bf16x8*>(
          Qg + (size_t)(q0 + qf * 64 + wv * 16 + lc) * HD + ks * 32 + lg * 8);

  // staging source offsets (constant per thread); dest is linear, src pre-swizzled
  int dstb[2], koff[2], voff[2];
#pragma unroll
  for (int i = 0; i < 2; ++i) {
    const int base = (wv * 2 + i) * 1024;      // byte base of this wave-issue
    const int lin  = base + lane * 16;         // this lane's dest byte
    dstb[i] = base;
    koff[i] = swzb(lin);                       // K tile is contiguous 8 KB
    voff[i] = (lin >> 7) * (TT * 2) + (swzb(lin) & 127);  // V^T row-strided
  }

  f32x4 o[4][2] = {};
  float m_run[2] = { -INFINITY, -INFINITY };
  float l_run[2] = { 0.f, 0.f };
  bf16* Pw = Ps[wv];

  const int ntiles = 2 * (qblk + 1);

  // prologue: stage tile 0 into buf 0
#pragma unroll
  for (int i = 0; i < 2; ++i) {
    gload_lds16((const bf16*)((const char*)Kg + koff[i]),
                (bf16*)((char*)Ks[0] + dstb[i]));
    gload_lds16((const bf16*)((const char*)Vg + voff[i]),
                (bf16*)((char*)Vs[0] + dstb[i]));
  }
  __syncthreads();

  int cur = 0;
  for (int ti = 0; ti < ntiles; ++ti) {
    const int k0 = ti * 64;

    // prefetch tile ti+1 into the other buffer (drained by the end barrier)
    if (ti + 1 < ntiles) {
      const size_t kb = (size_t)(ti + 1) * 8192;   // bytes into K slab
      const size_t vb = (size_t)(ti + 1) * 128;    // bytes into each V^T row
#pragma unroll
      for (int i = 0; i < 2; ++i) {
        gload_lds16((const bf16*)((const char*)Kg + kb + koff[i]),
                    (bf16*)((char*)Ks[cur ^ 1] + dstb[i]));
        gload_lds16((const bf16*)((const char*)Vg + vb + voff[i]),
                    (bf16*)((char*)Vs[cur ^ 1] + dstb[i]));
      }
    }

    const char* ksb = (const char*)Ks[cur];
    const char* vsb = (const char*)Vs[cur];

    // S^T = K Q^T : s[kvf][qf], lane holds kv = k0+kvf*16+lg*4+r, q = ...+lc
    f32x4 s[4][2] = {};
#pragma unroll
    for (int ks = 0; ks < 2; ++ks)
#pragma unroll
      for (int kvf = 0; kvf < 4; ++kvf) {
        const bf16x8 kf = *reinterpret_cast<const bf16x8*>(
            ksb + swzb((kvf * 16 + lc) * 128 + ks * 64 + lg * 16));
#pragma unroll
        for (int qf = 0; qf < 2; ++qf)
          s[kvf][qf] = __builtin_amdgcn_mfma_f32_16x16x32_bf16(kf, qreg[qf][ks],
                                                               s[kvf][qf], 0, 0, 0);
      }

    // causal mask (only tiles that can touch the diagonal)
#pragma unroll
    for (int qf = 0; qf < 2; ++qf) {
      const int qbase = q0 + qf * 64 + wv * 16;
      if (k0 + 63 > qbase) {
        const int q = qbase + lc;
#pragma unroll
        for (int kvf = 0; kvf < 4; ++kvf)
#pragma unroll
          for (int r = 0; r < 4; ++r)
            if (k0 + kvf * 16 + lg * 4 + r > q) s[kvf][qf][r] = -INFINITY;
      }
    }

    // online softmax (exp2 domain), per qf; q = lc layout, reduce across lg
    float alpha[2];
#pragma unroll
    for (int qf = 0; qf < 2; ++qf) {
      float rmax = -INFINITY;
#pragma unroll
      for (int kvf = 0; kvf < 4; ++kvf)
#pragma unroll
        for (int r = 0; r < 4; ++r) rmax = fmaxf(rmax, s[kvf][qf][r]);
      rmax = fmaxf(rmax, __shfl_xor(rmax, 16));
      rmax = fmaxf(rmax, __shfl_xor(rmax, 32));

      const float mn = fmaxf(m_run[qf], rmax);
      alpha[qf] = __builtin_amdgcn_exp2f(m_run[qf] - mn);
      m_run[qf] = mn;

      float rsum = 0.f;
#pragma unroll
      for (int kvf = 0; kvf < 4; ++kvf)
#pragma unroll
        for (int r = 0; r < 4; ++r) {
          const float p = __builtin_amdgcn_exp2f(s[kvf][qf][r] - mn);
          s[kvf][qf][r] = p;
          rsum += p;
        }
      rsum += __shfl_xor(rsum, 16);
      rsum += __shfl_xor(rsum, 32);
      l_run[qf] = l_run[qf] * alpha[qf] + rsum;
    }

    // rescale O (acc layout q = lg*4+r needs alpha from lane lg*4+r)
#pragma unroll
    for (int qf = 0; qf < 2; ++qf) {
      float ar[4];
#pragma unroll
      for (int r = 0; r < 4; ++r) ar[r] = __shfl(alpha[qf], lg * 4 + r);
#pragma unroll
      for (int df = 0; df < 4; ++df)
#pragma unroll
        for (int r = 0; r < 4; ++r) o[df][qf][r] *= ar[r];
    }

    // P pack to per-wave LDS: row q_local = qf*16+lc, col kv
#pragma unroll
    for (int qf = 0; qf < 2; ++qf)
#pragma unroll
      for (int kvf = 0; kvf < 4; ++kvf) {
        bf16x4 pk = { (bf16)s[kvf][qf][0], (bf16)s[kvf][qf][1],
                      (bf16)s[kvf][qf][2], (bf16)s[kvf][qf][3] };
        *reinterpret_cast<bf16x4*>(&Pw[(qf * 16 + lc) * 72 + kvf * 16 + lg * 4]) = pk;
      }

    // O += P V
#pragma unroll
    for (int ks = 0; ks < 2; ++ks) {
      bf16x8 pf[2];
#pragma unroll
      for (int qf = 0; qf < 2; ++qf)
        pf[qf] = *reinterpret_cast<const bf16x8*>(&Pw[(qf * 16 + lc) * 72 + ks * 32 + lg * 8]);
#pragma unroll
      for (int df = 0; df < 4; ++df) {
        const bf16x8 vf = *reinterpret_cast<const bf16x8*>(
            vsb + swzb((df * 16 + lc) * 128 + ks * 64 + lg * 16));
#pragma unroll
        for (int qf = 0; qf < 2; ++qf)
          o[df][qf] = __builtin_amdgcn_mfma_f32_16x16x32_bf16(pf[qf], vf,
                                                              o[df][qf], 0, 0, 0);
      }
    }

    __syncthreads();   // drains prefetch (vmcnt) + publishes P-buffer reuse
    cur ^= 1;
  }

  // normalize + write y[b*T + q][h*64 + d]
  const int b = bh >> 4, h = bh & 15;
#pragma unroll
  for (int qf = 0; qf < 2; ++qf) {
    const float linv = 1.f / fmaxf(l_run[qf], 1e-9f);
    float ir[4];
#pragma unroll
    for (int r = 0; r < 4; ++r) ir[r] = __shfl(linv, lg * 4 + r);
#pragma unroll
    for (int df = 0; df < 4; ++df)
#pragma unroll
      for (int r = 0; r < 4; ++r) {
        const int q = q0 + qf * 64 + wv * 16 + lg * 4 + r;
        Yb[((size_t)(b * TT + q)) * DM + h * HD + df * 16 + lc] =
            (bf16)(o[df][qf][r] * ir[r]);
      }
  }
}

// ---------------- output projection ----------------
__launch_bounds__(256, 2)
__global__ void gemm_out(const bf16* __restrict__ Y, const bf16* __restrict__ Wo,
                         float* __restrict__ Out) {
  __shared__ bf16 As[128 * 32];
  __shared__ bf16 Bs[128 * 32];
  const int tid  = threadIdx.x;
  const int lane = tid & 63;
  const int wv   = tid >> 6;
  const int lg   = lane >> 4, lc = lane & 15;
  const int m0   = blockIdx.x * 128;
  const int n0   = blockIdx.y * 128;
  const int wm = wv >> 1, wn = wv & 1;

  f32x4 acc[4][4] = {};

  for (int k0 = 0; k0 < DM; k0 += 32) {
#pragma unroll
    for (int c = 0; c < 2; ++c) {
      const int e   = wv * 512 + c * 2048 + lane * 8;
      const int row = e >> 5, col = e & 31;
      gload_lds16(Y  + (size_t)(m0 + row) * DM + k0 + col, &As[wv * 512 + c * 2048]);
      gload_lds16(Wo + (size_t)(n0 + row) * DM + k0 + col, &Bs[wv * 512 + c * 2048]);
    }
    __syncthreads();
    bf16x8 a[4], b[4];
#pragma unroll
    for (int i = 0; i < 4; ++i)
      a[i] = *reinterpret_cast<const bf16x8*>(&As[(wm * 64 + i * 16 + lc) * 32 + lg * 8]);
#pragma unroll
    for (int j = 0; j < 4; ++j)
      b[j] = *reinterpret_cast<const bf16x8*>(&Bs[(wn * 64 + j * 16 + lc) * 32 + lg * 8]);
#pragma unroll
    for (int i = 0; i < 4; ++i)
#pragma unroll
      for (int j = 0; j < 4; ++j)
        acc[i][j] = __builtin_amdgcn_mfma_f32_16x16x32_bf16(a[i], b[j], acc[i][j], 0, 0, 0);
    __syncthreads();
  }

#pragma unroll
  for (int i = 0; i < 4; ++i) {
    const int mg = m0 + wm * 64 + i * 16 + lg * 4;
#pragma unroll
    for (int j = 0; j < 4; ++j) {
      const int n = n0 + wn * 64 + j * 16 + lc;
#pragma unroll
      for (int r = 0; r < 4; ++r)
        Out[(size_t)(mg + r) * DM + n] = acc[i][j][r];
    }
  }
}

extern "C" void kernel_launch(void* const* d_in, const int* in_sizes, int n_in,
                              void* d_out, int out_size, void* d_ws, size_t ws_size,
                              hipStream_t stream) {
  const float* x  = (const float*)d_in[0];
  const float* Wq = (const float*)d_in[1];
  const float* Wk = (const float*)d_in[2];
  const float* Wv = (const float*)d_in[3];
  const float* Wo = (const float*)d_in[4];
  float* out = (float*)d_out;
  char* ws = (char*)d_ws;
  const size_t MB = 1024 * 1024;

  bf16* xb  = (bf16*)(ws + 0);        // 8 MB, reused as yb after QKV GEMM
  bf16* wqb = (bf16*)(ws + 8  * MB);
  bf16* wkb = (bf16*)(ws + 10 * MB);
  bf16* wvb = (bf16*)(ws + 12 * MB);
  bf16* wob = (bf16*)(ws + 14 * MB);
  bf16* Qb  = (bf16*)(ws + 16 * MB);  // [32,2048,64]
  bf16* Kb  = (bf16*)(ws + 24 * MB);
  bf16* Vtb = (bf16*)(ws + 32 * MB);  // [32,64,2048]
  bf16* yb  = xb;

  cvt_all<<<8192, 256, 0, stream>>>(x, Wq, Wk, Wv, Wo, xb, wqb, wkb, wvb, wob);
  gemm_qkv<<<dim3(32, 24), 256, 0, stream>>>(xb, wqb, wkb, wvb, Qb, Kb, Vtb);
  attn_fwd<<<512, 256, 0, stream>>>(Qb, Kb, Vtb, yb);
  gemm_out<<<dim3(32, 8), 256, 0, stream>>>(yb, wob, out);
}

// Round 4
// 114.332 us; speedup vs baseline: 1.7165x; 1.0403x over previous
//
#include <hip/hip_runtime.h>
#include <hip/hip_bf16.h>
#include <stdint.h>

typedef __bf16 bf16;
typedef __bf16 bf16x8 __attribute__((ext_vector_type(8)));
typedef __bf16 bf16x4 __attribute__((ext_vector_type(4)));
typedef float  f32x4  __attribute__((ext_vector_type(4)));

#define DM 1024
#define NH 16
#define HD 64
#define TT 2048

// log2(e)/8 : puts QK^T scores directly in exp2 domain
#define QSCALE 0.18033688011112042f

__global__ void cvt_all(const float* __restrict__ x,  const float* __restrict__ wq,
                        const float* __restrict__ wk, const float* __restrict__ wv,
                        const float* __restrict__ wo,
                        bf16* __restrict__ xb,  bf16* __restrict__ wqb,
                        bf16* __restrict__ wkb, bf16* __restrict__ wvb,
                        bf16* __restrict__ wob) {
  const int i = (blockIdx.x * blockDim.x + threadIdx.x) * 4;
  const float* src; bf16* dst; int off;
  if (i < 4194304)      { src = x;  dst = xb;  off = i; }
  else {
    const int j = i - 4194304;
    const int w = j >> 20;
    off = j & 1048575;
    src = (w == 0) ? wq : (w == 1) ? wk : (w == 2) ? wv : wo;
    dst = (w == 0) ? wqb : (w == 1) ? wkb : (w == 2) ? wvb : wob;
  }
  const float4 v = *reinterpret_cast<const float4*>(src + off);
  bf16x4 o = { (bf16)v.x, (bf16)v.y, (bf16)v.z, (bf16)v.w };
  *reinterpret_cast<bf16x4*>(dst + off) = o;
}

static __device__ __forceinline__ void gload_lds16(const bf16* g, bf16* l) {
  __builtin_amdgcn_global_load_lds(
      (__attribute__((address_space(1))) void*)g,
      (__attribute__((address_space(3))) void*)l, 16, 0, 0);
}

// XOR swizzle: spreads the 8 16B-slots of a 128B row across banks by row
static __device__ __forceinline__ int swzb(int lin) {
  return lin ^ (((lin >> 7) & 7) << 4);
}

// ---------------- QKV projection (m97-style) ----------------
__launch_bounds__(256, 3)
__global__ void gemm_qkv(const bf16* __restrict__ X, const bf16* __restrict__ Wq,
                         const bf16* __restrict__ Wk, const bf16* __restrict__ Wv,
                         bf16* __restrict__ Qb, bf16* __restrict__ Kb,
                         bf16* __restrict__ Vtb) {
  __shared__ bf16 As[128 * 32];
  __shared__ bf16 Bs[128 * 32];
  const int tid  = threadIdx.x;
  const int lane = tid & 63;
  const int wv   = tid >> 6;
  const int lg   = lane >> 4, lc = lane & 15;
  const int m0   = blockIdx.x * 128;
  const int ng   = blockIdx.y * 128;
  const int which = ng >> 10;                 // 0=Q 1=K 2=V
  const bf16* W = (which == 0) ? Wq : ((which == 1) ? Wk : Wv);
  const int n0 = ng & 1023;
  const int wm = wv >> 1, wn = wv & 1;

  f32x4 acc[4][4] = {};

  for (int k0 = 0; k0 < DM; k0 += 32) {
#pragma unroll
    for (int c = 0; c < 2; ++c) {
      const int e   = wv * 512 + c * 2048 + lane * 8;
      const int row = e >> 5, col = e & 31;
      gload_lds16(X + (size_t)(m0 + row) * DM + k0 + col, &As[wv * 512 + c * 2048]);
      gload_lds16(W + (size_t)(n0 + row) * DM + k0 + col, &Bs[wv * 512 + c * 2048]);
    }
    __syncthreads();
    bf16x8 a[4], b[4];
#pragma unroll
    for (int i = 0; i < 4; ++i)
      a[i] = *reinterpret_cast<const bf16x8*>(&As[(wm * 64 + i * 16 + lc) * 32 + lg * 8]);
#pragma unroll
    for (int j = 0; j < 4; ++j)
      b[j] = *reinterpret_cast<const bf16x8*>(&Bs[(wn * 64 + j * 16 + lc) * 32 + lg * 8]);
#pragma unroll
    for (int i = 0; i < 4; ++i)
#pragma unroll
      for (int j = 0; j < 4; ++j)
        acc[i][j] = __builtin_amdgcn_mfma_f32_16x16x32_bf16(a[i], b[j], acc[i][j], 0, 0, 0);
    __syncthreads();
  }

#pragma unroll
  for (int i = 0; i < 4; ++i) {
    const int mg = m0 + wm * 64 + i * 16 + lg * 4;
    const int bb = mg >> 11, t = mg & 2047;
#pragma unroll
    for (int j = 0; j < 4; ++j) {
      const int nl = n0 + wn * 64 + j * 16 + lc;
      const int h = nl >> 6, d = nl & 63;
      const int bh = bb * NH + h;
      const f32x4 v = acc[i][j];
      if (which == 0) {
        bf16* p = Qb + ((size_t)bh * TT + t) * HD + d;
#pragma unroll
        for (int r = 0; r < 4; ++r) p[r * HD] = (bf16)(v[r] * QSCALE);
      } else if (which == 1) {
        bf16* p = Kb + ((size_t)bh * TT + t) * HD + d;
#pragma unroll
        for (int r = 0; r < 4; ++r) p[r * HD] = (bf16)v[r];
      } else {
        bf16x4 pk = { (bf16)v[0], (bf16)v[1], (bf16)v[2], (bf16)v[3] };
        *reinterpret_cast<bf16x4*>(Vtb + ((size_t)bh * HD + d) * TT + t) = pk;
      }
    }
  }
}

// ---------------- flash attention ----------------
// 256 identical blocks: bh = bid&31, pr = bid>>5. Each block processes qblk
// pair (8+pr, 7-pr) sequentially -> always 34 kv-tiles -> perfect balance
// under any dispatch. 8 waves x 16 q-rows per 128-row qblk. 2-phase LDS
// pipeline, XOR-swizzled K/V tiles, swapped QK^T, O^T accumulation.
#define KPAD 72

__launch_bounds__(512, 2)
__global__ void attn_fwd(const bf16* __restrict__ Qb, const bf16* __restrict__ Kb,
                         const bf16* __restrict__ Vtb, bf16* __restrict__ Yb) {
  __shared__ bf16 Ks[2][4096];     // [buf][64 kv x 64 d] swizzled
  __shared__ bf16 Vs[2][4096];     // [buf][64 d x 64 kv] swizzled
  __shared__ bf16 Ps[8][16 * KPAD];

  const int tid  = threadIdx.x;
  const int lane = tid & 63;
  const int wv   = tid >> 6;       // 0..7
  const int lg   = lane >> 4;
  const int lc   = lane & 15;
  const int bh   = blockIdx.x & 31;
  const int pr   = blockIdx.x >> 5;            // 0..7
  const int qblkA = 8 + pr, qblkB = 7 - pr;
  const int nt0  = 2 * qblkA + 2;              // tiles in phase A; total = 34

  const bf16* Qg = Qb  + (size_t)bh * TT * HD;
  const bf16* Kg = Kb  + (size_t)bh * TT * HD;
  const bf16* Vg = Vtb + (size_t)bh * HD * TT;

  // preload Q fragments for both phases (B-operand; pre-scaled by QSCALE)
  bf16x8 qA0, qA1, qB0, qB1;
  qA0 = *reinterpret_cast<const bf16x8*>(Qg + (size_t)(qblkA * 128 + wv * 16 + lc) * HD + 0  + lg * 8);
  qA1 = *reinterpret_cast<const bf16x8*>(Qg + (size_t)(qblkA * 128 + wv * 16 + lc) * HD + 32 + lg * 8);
  qB0 = *reinterpret_cast<const bf16x8*>(Qg + (size_t)(qblkB * 128 + wv * 16 + lc) * HD + 0  + lg * 8);
  qB1 = *reinterpret_cast<const bf16x8*>(Qg + (size_t)(qblkB * 128 + wv * 16 + lc) * HD + 32 + lg * 8);

  // staging offsets: dest linear (wave-uniform base + lane*16), src pre-swizzled
  const int lin  = tid * 16;
  const int dstb = wv * 1024;                       // wave-uniform dest byte
  const int koff = swzb(lin);
  const int voff = (lin >> 7) * (TT * 2) + (swzb(lin) & 127);

  auto STAGE = [&](int b, int kv) {
    gload_lds16((const bf16*)((const char*)Kg + (size_t)kv * 8192 + koff),
                (bf16*)((char*)Ks[b] + dstb));
    gload_lds16((const bf16*)((const char*)Vg + (size_t)kv * 128 + voff),
                (bf16*)((char*)Vs[b] + dstb));
  };

  f32x4 o[4] = {};                 // O^T: o[df] row d = df*16+lg*4+r, col q = lc
  float m_run = -INFINITY, l_run = 0.f;
  int   q0 = qblkA * 128;
  bf16x8 qf0 = qA0, qf1 = qA1;
  bf16* Pw = Ps[wv];
  const int b_ = bh >> 4, h_ = bh & 15;

  STAGE(0, 0);
  __syncthreads();

  int cur = 0;
  for (int ti = 0; ti < 34; ++ti) {
    const int kv = (ti < nt0) ? ti : ti - nt0;
    const int k0 = kv * 64;

    if (ti + 1 < 34) {
      const int tn = ti + 1;
      STAGE(cur ^ 1, (tn < nt0) ? tn : tn - nt0);
    }

    const char* ksb = (const char*)Ks[cur];
    const char* vsb = (const char*)Vs[cur];

    // S^T = K Q^T : s[kvf], lane holds kv = k0+kvf*16+lg*4+r, q = q0+wv*16+lc
    f32x4 s[4] = {};
#pragma unroll
    for (int kvf = 0; kvf < 4; ++kvf) {
      const bf16x8 k0f = *reinterpret_cast<const bf16x8*>(
          ksb + swzb((kvf * 16 + lc) * 128 + lg * 16));
      s[kvf] = __builtin_amdgcn_mfma_f32_16x16x32_bf16(k0f, qf0, s[kvf], 0, 0, 0);
      const bf16x8 k1f = *reinterpret_cast<const bf16x8*>(
          ksb + swzb((kvf * 16 + lc) * 128 + 64 + lg * 16));
      s[kvf] = __builtin_amdgcn_mfma_f32_16x16x32_bf16(k1f, qf1, s[kvf], 0, 0, 0);
    }

    // causal mask (wave-uniform guard)
    const int qw = q0 + wv * 16;
    if (k0 + 63 > qw) {
      const int q = qw + lc;
#pragma unroll
      for (int kvf = 0; kvf < 4; ++kvf)
#pragma unroll
        for (int r = 0; r < 4; ++r)
          if (k0 + kvf * 16 + lg * 4 + r > q) s[kvf][r] = -INFINITY;
    }

    // online softmax (exp2 domain); stats live in q = lc layout
    float rmax = -INFINITY;
#pragma unroll
    for (int kvf = 0; kvf < 4; ++kvf)
#pragma unroll
      for (int r = 0; r < 4; ++r) rmax = fmaxf(rmax, s[kvf][r]);
    rmax = fmaxf(rmax, __shfl_xor(rmax, 16));
    rmax = fmaxf(rmax, __shfl_xor(rmax, 32));

    const float mn = fmaxf(m_run, rmax);
    const float alpha = __builtin_amdgcn_exp2f(m_run - mn);
    m_run = mn;

    float rsum = 0.f;
#pragma unroll
    for (int kvf = 0; kvf < 4; ++kvf)
#pragma unroll
      for (int r = 0; r < 4; ++r) {
        const float p = __builtin_amdgcn_exp2f(s[kvf][r] - mn);
        s[kvf][r] = p;
        rsum += p;
      }
    rsum += __shfl_xor(rsum, 16);
    rsum += __shfl_xor(rsum, 32);
    l_run = l_run * alpha + rsum;

    // rescale O^T: col q = lc -> alpha applies uniformly per lane (no shfl)
#pragma unroll
    for (int df = 0; df < 4; ++df)
#pragma unroll
      for (int r = 0; r < 4; ++r) o[df][r] *= alpha;

    // P -> per-wave LDS: row q=lc, col kv (for B-operand re-read)
#pragma unroll
    for (int kvf = 0; kvf < 4; ++kvf) {
      bf16x4 pk = { (bf16)s[kvf][0], (bf16)s[kvf][1],
                    (bf16)s[kvf][2], (bf16)s[kvf][3] };
      *reinterpret_cast<bf16x4*>(&Pw[lc * KPAD + kvf * 16 + lg * 4]) = pk;
    }

    // O^T += V^T P : A = V^T frag (row d=..+lc), B = P frag (col q=lc)
#pragma unroll
    for (int ks = 0; ks < 2; ++ks) {
      const bf16x8 pf = *reinterpret_cast<const bf16x8*>(
          &Pw[lc * KPAD + ks * 32 + lg * 8]);
#pragma unroll
      for (int df = 0; df < 4; ++df) {
        const bf16x8 vf = *reinterpret_cast<const bf16x8*>(
            vsb + swzb((df * 16 + lc) * 128 + ks * 64 + lg * 16));
        o[df] = __builtin_amdgcn_mfma_f32_16x16x32_bf16(vf, pf, o[df], 0, 0, 0);
      }
    }

    // phase A -> B switch (before the barrier; global stores only)
    if (ti == nt0 - 1) {
      const float linv = 1.f / fmaxf(l_run, 1e-9f);
      const int q = q0 + wv * 16 + lc;
#pragma unroll
      for (int df = 0; df < 4; ++df) {
        bf16x4 yv = { (bf16)(o[df][0] * linv), (bf16)(o[df][1] * linv),
                      (bf16)(o[df][2] * linv), (bf16)(o[df][3] * linv) };
        *reinterpret_cast<bf16x4*>(
            Yb + ((size_t)(b_ * TT + q)) * DM + h_ * HD + df * 16 + lg * 4) = yv;
        o[df] = f32x4{};
      }
      m_run = -INFINITY; l_run = 0.f;
      q0 = qblkB * 128;
      qf0 = qB0; qf1 = qB1;
    }

    __syncthreads();   // drains prefetch + publishes buffer swap
    cur ^= 1;
  }

  // phase B writeback
  {
    const float linv = 1.f / fmaxf(l_run, 1e-9f);
    const int q = q0 + wv * 16 + lc;
#pragma unroll
    for (int df = 0; df < 4; ++df) {
      bf16x4 yv = { (bf16)(o[df][0] * linv), (bf16)(o[df][1] * linv),
                    (bf16)(o[df][2] * linv), (bf16)(o[df][3] * linv) };
      *reinterpret_cast<bf16x4*>(
          Yb + ((size_t)(b_ * TT + q)) * DM + h_ * HD + df * 16 + lg * 4) = yv;
    }
  }
}

// ---------------- output projection ----------------
__launch_bounds__(256, 2)
__global__ void gemm_out(const bf16* __restrict__ Y, const bf16* __restrict__ Wo,
                         float* __restrict__ Out) {
  __shared__ bf16 As[128 * 32];
  __shared__ bf16 Bs[128 * 32];
  const int tid  = threadIdx.x;
  const int lane = tid & 63;
  const int wv   = tid >> 6;
  const int lg   = lane >> 4, lc = lane & 15;
  const int m0   = blockIdx.x * 128;
  const int n0   = blockIdx.y * 128;
  const int wm = wv >> 1, wn = wv & 1;

  f32x4 acc[4][4] = {};

  for (int k0 = 0; k0 < DM; k0 += 32) {
#pragma unroll
    for (int c = 0; c < 2; ++c) {
      const int e   = wv * 512 + c * 2048 + lane * 8;
      const int row = e >> 5, col = e & 31;
      gload_lds16(Y  + (size_t)(m0 + row) * DM + k0 + col, &As[wv * 512 + c * 2048]);
      gload_lds16(Wo + (size_t)(n0 + row) * DM + k0 + col, &Bs[wv * 512 + c * 2048]);
    }
    __syncthreads();
    bf16x8 a[4], b[4];
#pragma unroll
    for (int i = 0; i < 4; ++i)
      a[i] = *reinterpret_cast<const bf16x8*>(&As[(wm * 64 + i * 16 + lc) * 32 + lg * 8]);
#pragma unroll
    for (int j = 0; j < 4; ++j)
      b[j] = *reinterpret_cast<const bf16x8*>(&Bs[(wn * 64 + j * 16 + lc) * 32 + lg * 8]);
#pragma unroll
    for (int i = 0; i < 4; ++i)
#pragma unroll
      for (int j = 0; j < 4; ++j)
        acc[i][j] = __builtin_amdgcn_mfma_f32_16x16x32_bf16(a[i], b[j], acc[i][j], 0, 0, 0);
    __syncthreads();
  }

#pragma unroll
  for (int i = 0; i < 4; ++i) {
    const int mg = m0 + wm * 64 + i * 16 + lg * 4;
#pragma unroll
    for (int j = 0; j < 4; ++j) {
      const int n = n0 + wn * 64 + j * 16 + lc;
#pragma unroll
      for (int r = 0; r < 4; ++r)
        Out[(size_t)(mg + r) * DM + n] = acc[i][j][r];
    }
  }
}

extern "C" void kernel_launch(void* const* d_in, const int* in_sizes, int n_in,
                              void* d_out, int out_size, void* d_ws, size_t ws_size,
                              hipStream_t stream) {
  const float* x  = (const float*)d_in[0];
  const float* Wq = (const float*)d_in[1];
  const float* Wk = (const float*)d_in[2];
  const float* Wv = (const float*)d_in[3];
  const float* Wo = (const float*)d_in[4];
  float* out = (float*)d_out;
  char* ws = (char*)d_ws;
  const size_t MB = 1024 * 1024;

  bf16* xb  = (bf16*)(ws + 0);        // 8 MB, reused as yb after QKV GEMM
  bf16* wqb = (bf16*)(ws + 8  * MB);
  bf16* wkb = (bf16*)(ws + 10 * MB);
  bf16* wvb = (bf16*)(ws + 12 * MB);
  bf16* wob = (bf16*)(ws + 14 * MB);
  bf16* Qb  = (bf16*)(ws + 16 * MB);  // [32,2048,64]
  bf16* Kb  = (bf16*)(ws + 24 * MB);
  bf16* Vtb = (bf16*)(ws + 32 * MB);  // [32,64,2048]
  bf16* yb  = xb;

  cvt_all<<<8192, 256, 0, stream>>>(x, Wq, Wk, Wv, Wo, xb, wqb, wkb, wvb, wob);
  gemm_qkv<<<dim3(32, 24), 256, 0, stream>>>(xb, wqb, wkb, wvb, Qb, Kb, Vtb);
  attn_fwd<<<256, 512, 0, stream>>>(Qb, Kb, Vtb, yb);
  gemm_out<<<dim3(32, 8), 256, 0, stream>>>(yb, wob, out);
}

// Round 5
// 110.663 us; speedup vs baseline: 1.7734x; 1.0332x over previous
//
#include <hip/hip_runtime.h>
#include <hip/hip_bf16.h>
#include <stdint.h>

typedef __bf16 bf16;
typedef __bf16 bf16x8 __attribute__((ext_vector_type(8)));
typedef __bf16 bf16x4 __attribute__((ext_vector_type(4)));
typedef float  f32x4  __attribute__((ext_vector_type(4)));

#define DM 1024
#define NH 16
#define HD 64
#define TT 2048

// log2(e)/8 : puts QK^T scores directly in exp2 domain
#define QSCALE 0.18033688011112042f

__global__ void cvt_all(const float* __restrict__ x,  const float* __restrict__ wq,
                        const float* __restrict__ wk, const float* __restrict__ wv,
                        const float* __restrict__ wo,
                        bf16* __restrict__ xb,  bf16* __restrict__ wqb,
                        bf16* __restrict__ wkb, bf16* __restrict__ wvb,
                        bf16* __restrict__ wob) {
  const int i = (blockIdx.x * blockDim.x + threadIdx.x) * 4;
  const float* src; bf16* dst; int off;
  if (i < 4194304)      { src = x;  dst = xb;  off = i; }
  else {
    const int j = i - 4194304;
    const int w = j >> 20;
    off = j & 1048575;
    src = (w == 0) ? wq : (w == 1) ? wk : (w == 2) ? wv : wo;
    dst = (w == 0) ? wqb : (w == 1) ? wkb : (w == 2) ? wvb : wob;
  }
  const float4 v = *reinterpret_cast<const float4*>(src + off);
  bf16x4 o = { (bf16)v.x, (bf16)v.y, (bf16)v.z, (bf16)v.w };
  *reinterpret_cast<bf16x4*>(dst + off) = o;
}

static __device__ __forceinline__ void gload_lds16(const bf16* g, bf16* l) {
  __builtin_amdgcn_global_load_lds(
      (__attribute__((address_space(1))) void*)g,
      (__attribute__((address_space(3))) void*)l, 16, 0, 0);
}

// XOR swizzle: spreads the 8 16B-slots of a 128B row across banks by row
static __device__ __forceinline__ int swzb(int lin) {
  return lin ^ (((lin >> 7) & 7) << 4);
}

// ---------------- QKV projection (m97-style) ----------------
__launch_bounds__(256, 3)
__global__ void gemm_qkv(const bf16* __restrict__ X, const bf16* __restrict__ Wq,
                         const bf16* __restrict__ Wk, const bf16* __restrict__ Wv,
                         bf16* __restrict__ Qb, bf16* __restrict__ Kb,
                         bf16* __restrict__ Vtb) {
  __shared__ bf16 As[128 * 32];
  __shared__ bf16 Bs[128 * 32];
  const int tid  = threadIdx.x;
  const int lane = tid & 63;
  const int wv   = tid >> 6;
  const int lg   = lane >> 4, lc = lane & 15;
  const int m0   = blockIdx.x * 128;
  const int ng   = blockIdx.y * 128;
  const int which = ng >> 10;                 // 0=Q 1=K 2=V
  const bf16* W = (which == 0) ? Wq : ((which == 1) ? Wk : Wv);
  const int n0 = ng & 1023;
  const int wm = wv >> 1, wn = wv & 1;

  f32x4 acc[4][4] = {};

  for (int k0 = 0; k0 < DM; k0 += 32) {
#pragma unroll
    for (int c = 0; c < 2; ++c) {
      const int e   = wv * 512 + c * 2048 + lane * 8;
      const int row = e >> 5, col = e & 31;
      gload_lds16(X + (size_t)(m0 + row) * DM + k0 + col, &As[wv * 512 + c * 2048]);
      gload_lds16(W + (size_t)(n0 + row) * DM + k0 + col, &Bs[wv * 512 + c * 2048]);
    }
    __syncthreads();
    bf16x8 a[4], b[4];
#pragma unroll
    for (int i = 0; i < 4; ++i)
      a[i] = *reinterpret_cast<const bf16x8*>(&As[(wm * 64 + i * 16 + lc) * 32 + lg * 8]);
#pragma unroll
    for (int j = 0; j < 4; ++j)
      b[j] = *reinterpret_cast<const bf16x8*>(&Bs[(wn * 64 + j * 16 + lc) * 32 + lg * 8]);
#pragma unroll
    for (int i = 0; i < 4; ++i)
#pragma unroll
      for (int j = 0; j < 4; ++j)
        acc[i][j] = __builtin_amdgcn_mfma_f32_16x16x32_bf16(a[i], b[j], acc[i][j], 0, 0, 0);
    __syncthreads();
  }

#pragma unroll
  for (int i = 0; i < 4; ++i) {
    const int mg = m0 + wm * 64 + i * 16 + lg * 4;
    const int bb = mg >> 11, t = mg & 2047;
#pragma unroll
    for (int j = 0; j < 4; ++j) {
      const int nl = n0 + wn * 64 + j * 16 + lc;
      const int h = nl >> 6, d = nl & 63;
      const int bh = bb * NH + h;
      const f32x4 v = acc[i][j];
      if (which == 0) {
        bf16* p = Qb + ((size_t)bh * TT + t) * HD + d;
#pragma unroll
        for (int r = 0; r < 4; ++r) p[r * HD] = (bf16)(v[r] * QSCALE);
      } else if (which == 1) {
        bf16* p = Kb + ((size_t)bh * TT + t) * HD + d;
#pragma unroll
        for (int r = 0; r < 4; ++r) p[r * HD] = (bf16)v[r];
      } else {
        bf16x4 pk = { (bf16)v[0], (bf16)v[1], (bf16)v[2], (bf16)v[3] };
        *reinterpret_cast<bf16x4*>(Vtb + ((size_t)bh * HD + d) * TT + t) = pk;
      }
    }
  }
}

// ---------------- flash attention ----------------
// 512 identical blocks: bh = bid&31, p = bid>>5 (0..15). Block processes
// 64-row qblk pair (16+p, 15-p) sequentially -> always 33 kv-tiles.
// 4 waves x 16 q-rows. Counted-vmcnt 2-phase pipeline (T4): prefetch loads
// stay in flight across barriers. XOR-swizzled K/V LDS, swapped QK^T,
// O^T accumulation.
#define KPAD 72

__launch_bounds__(256, 2)
__global__ void attn_fwd(const bf16* __restrict__ Qb, const bf16* __restrict__ Kb,
                         const bf16* __restrict__ Vtb, bf16* __restrict__ Yb) {
  __shared__ bf16 Ks[2][4096];     // [buf][64 kv x 64 d] swizzled
  __shared__ bf16 Vs[2][4096];     // [buf][64 d x 64 kv] swizzled
  __shared__ bf16 Ps[4][16 * KPAD];

  const int tid  = threadIdx.x;
  const int lane = tid & 63;
  const int wv   = tid >> 6;       // 0..3
  const int lg   = lane >> 4;
  const int lc   = lane & 15;
  const int bh   = blockIdx.x & 31;
  const int pr   = blockIdx.x >> 5;            // 0..15
  const int qblkA = 16 + pr, qblkB = 15 - pr;  // 64-row q blocks
  const int nt0  = qblkA + 1;                  // tiles in phase A; total = 33
  const int NT   = 33;

  const bf16* Qg = Qb  + (size_t)bh * TT * HD;
  const bf16* Kg = Kb  + (size_t)bh * TT * HD;
  const bf16* Vg = Vtb + (size_t)bh * HD * TT;

  // preload Q fragments for both phases (B-operand; pre-scaled by QSCALE)
  bf16x8 qA0, qA1, qB0, qB1;
  qA0 = *reinterpret_cast<const bf16x8*>(Qg + (size_t)(qblkA * 64 + wv * 16 + lc) * HD + 0  + lg * 8);
  qA1 = *reinterpret_cast<const bf16x8*>(Qg + (size_t)(qblkA * 64 + wv * 16 + lc) * HD + 32 + lg * 8);
  qB0 = *reinterpret_cast<const bf16x8*>(Qg + (size_t)(qblkB * 64 + wv * 16 + lc) * HD + 0  + lg * 8);
  qB1 = *reinterpret_cast<const bf16x8*>(Qg + (size_t)(qblkB * 64 + wv * 16 + lc) * HD + 32 + lg * 8);

  // staging offsets: dest linear (wave-uniform base + lane*16), src pre-swizzled
  int dstb[2], koff[2], voff[2];
#pragma unroll
  for (int c = 0; c < 2; ++c) {
    const int base = (wv * 2 + c) * 1024;        // byte base of this issue
    const int lin  = base + lane * 16;
    dstb[c] = base;
    koff[c] = swzb(lin);
    voff[c] = (lin >> 7) * (TT * 2) + (swzb(lin) & 127);
  }

  auto STAGE = [&](int b, int kv) {
#pragma unroll
    for (int c = 0; c < 2; ++c) {
      gload_lds16((const bf16*)((const char*)Kg + (size_t)kv * 8192 + koff[c]),
                  (bf16*)((char*)Ks[b] + dstb[c]));
      gload_lds16((const bf16*)((const char*)Vg + (size_t)kv * 128 + voff[c]),
                  (bf16*)((char*)Vs[b] + dstb[c]));
    }
  };

  f32x4 o[4] = {};                 // O^T: o[df] row d = df*16+lg*4+r, col q = lc
  float m_run = -INFINITY, l_run = 0.f;
  int   q0 = qblkA * 64;
  bf16x8 qf0 = qA0, qf1 = qA1;
  bf16* Pw = Ps[wv];
  const int b_ = bh >> 4, h_ = bh & 15;

  STAGE(0, 0);                     // 4 loads outstanding

  int cur = 0;
  for (int ti = 0; ti < NT; ++ti) {
    const int kv = (ti < nt0) ? ti : ti - nt0;
    const int k0 = kv * 64;

    // prefetch next tile, then wait only for the CURRENT tile's 4 loads
    if (ti + 1 < NT) {
      const int tn = ti + 1;
      STAGE(cur ^ 1, (tn < nt0) ? tn : tn - nt0);
      asm volatile("s_waitcnt vmcnt(4)" ::: "memory");
    } else {
      asm volatile("s_waitcnt vmcnt(0)" ::: "memory");
    }
    __builtin_amdgcn_s_barrier();          // all waves' current-tile loads landed
    __builtin_amdgcn_sched_barrier(0);

    const char* ksb = (const char*)Ks[cur];
    const char* vsb = (const char*)Vs[cur];

    // S^T = K Q^T : s[kvf], lane holds kv = k0+kvf*16+lg*4+r, q = q0+wv*16+lc
    f32x4 s[4] = {};
    __builtin_amdgcn_s_setprio(1);
#pragma unroll
    for (int kvf = 0; kvf < 4; ++kvf) {
      const bf16x8 k0f = *reinterpret_cast<const bf16x8*>(
          ksb + swzb((kvf * 16 + lc) * 128 + lg * 16));
      s[kvf] = __builtin_amdgcn_mfma_f32_16x16x32_bf16(k0f, qf0, s[kvf], 0, 0, 0);
      const bf16x8 k1f = *reinterpret_cast<const bf16x8*>(
          ksb + swzb((kvf * 16 + lc) * 128 + 64 + lg * 16));
      s[kvf] = __builtin_amdgcn_mfma_f32_16x16x32_bf16(k1f, qf1, s[kvf], 0, 0, 0);
    }
    __builtin_amdgcn_s_setprio(0);

    // causal mask (only the diagonal tile per phase)
    const int qw = q0 + wv * 16;
    if (k0 + 63 > qw) {
      const int q = qw + lc;
#pragma unroll
      for (int kvf = 0; kvf < 4; ++kvf)
#pragma unroll
        for (int r = 0; r < 4; ++r)
          if (k0 + kvf * 16 + lg * 4 + r > q) s[kvf][r] = -INFINITY;
    }

    // online softmax (exp2 domain); stats live in q = lc layout. Tree reduce.
    float t0 = fmaxf(fmaxf(s[0][0], s[0][1]), fmaxf(s[0][2], s[0][3]));
    float t1 = fmaxf(fmaxf(s[1][0], s[1][1]), fmaxf(s[1][2], s[1][3]));
    float t2 = fmaxf(fmaxf(s[2][0], s[2][1]), fmaxf(s[2][2], s[2][3]));
    float t3 = fmaxf(fmaxf(s[3][0], s[3][1]), fmaxf(s[3][2], s[3][3]));
    float rmax = fmaxf(fmaxf(t0, t1), fmaxf(t2, t3));
    rmax = fmaxf(rmax, __shfl_xor(rmax, 16));
    rmax = fmaxf(rmax, __shfl_xor(rmax, 32));

    const float mn = fmaxf(m_run, rmax);
    const float alpha = __builtin_amdgcn_exp2f(m_run - mn);
    m_run = mn;

#pragma unroll
    for (int kvf = 0; kvf < 4; ++kvf)
#pragma unroll
      for (int r = 0; r < 4; ++r)
        s[kvf][r] = __builtin_amdgcn_exp2f(s[kvf][r] - mn);

    float u0 = (s[0][0] + s[0][1]) + (s[0][2] + s[0][3]);
    float u1 = (s[1][0] + s[1][1]) + (s[1][2] + s[1][3]);
    float u2 = (s[2][0] + s[2][1]) + (s[2][2] + s[2][3]);
    float u3 = (s[3][0] + s[3][1]) + (s[3][2] + s[3][3]);
    float rsum = (u0 + u1) + (u2 + u3);
    rsum += __shfl_xor(rsum, 16);
    rsum += __shfl_xor(rsum, 32);
    l_run = l_run * alpha + rsum;

    // rescale O^T: col q = lc -> alpha applies uniformly per lane (no shfl)
#pragma unroll
    for (int df = 0; df < 4; ++df)
#pragma unroll
      for (int r = 0; r < 4; ++r) o[df][r] *= alpha;

    // P -> per-wave LDS: row q=lc, col kv (for B-operand re-read)
#pragma unroll
    for (int kvf = 0; kvf < 4; ++kvf) {
      bf16x4 pk = { (bf16)s[kvf][0], (bf16)s[kvf][1],
                    (bf16)s[kvf][2], (bf16)s[kvf][3] };
      *reinterpret_cast<bf16x4*>(&Pw[lc * KPAD + kvf * 16 + lg * 4]) = pk;
    }

    // O^T += V^T P : A = V^T frag (row d=..+lc), B = P frag (col q=lc)
    __builtin_amdgcn_s_setprio(1);
#pragma unroll
    for (int ks = 0; ks < 2; ++ks) {
      const bf16x8 pf = *reinterpret_cast<const bf16x8*>(
          &Pw[lc * KPAD + ks * 32 + lg * 8]);
#pragma unroll
      for (int df = 0; df < 4; ++df) {
        const bf16x8 vf = *reinterpret_cast<const bf16x8*>(
            vsb + swzb((df * 16 + lc) * 128 + ks * 64 + lg * 16));
        o[df] = __builtin_amdgcn_mfma_f32_16x16x32_bf16(vf, pf, o[df], 0, 0, 0);
      }
    }
    __builtin_amdgcn_s_setprio(0);

    // phase A -> B switch (global stores only; sits between barriers)
    if (ti == nt0 - 1) {
      const float linv = 1.f / fmaxf(l_run, 1e-9f);
      const int q = q0 + wv * 16 + lc;
#pragma unroll
      for (int df = 0; df < 4; ++df) {
        bf16x4 yv = { (bf16)(o[df][0] * linv), (bf16)(o[df][1] * linv),
                      (bf16)(o[df][2] * linv), (bf16)(o[df][3] * linv) };
        *reinterpret_cast<bf16x4*>(
            Yb + ((size_t)(b_ * TT + q)) * DM + h_ * HD + df * 16 + lg * 4) = yv;
        o[df] = f32x4{};
      }
      m_run = -INFINITY; l_run = 0.f;
      q0 = qblkB * 64;
      qf0 = qB0; qf1 = qB1;
    }

    __builtin_amdgcn_s_barrier();    // all waves done reading buffer `cur`
    cur ^= 1;
  }

  // phase B writeback
  {
    const float linv = 1.f / fmaxf(l_run, 1e-9f);
    const int q = q0 + wv * 16 + lc;
#pragma unroll
    for (int df = 0; df < 4; ++df) {
      bf16x4 yv = { (bf16)(o[df][0] * linv), (bf16)(o[df][1] * linv),
                    (bf16)(o[df][2] * linv), (bf16)(o[df][3] * linv) };
      *reinterpret_cast<bf16x4*>(
          Yb + ((size_t)(b_ * TT + q)) * DM + h_ * HD + df * 16 + lg * 4) = yv;
    }
  }
}

// ---------------- output projection (64x128 tiles, 512 blocks = 2/CU) -------
__launch_bounds__(256, 2)
__global__ void gemm_out(const bf16* __restrict__ Y, const bf16* __restrict__ Wo,
                         float* __restrict__ Out) {
  __shared__ bf16 As[64 * 32];
  __shared__ bf16 Bs[128 * 32];
  const int tid  = threadIdx.x;
  const int lane = tid & 63;
  const int wv   = tid >> 6;
  const int lg   = lane >> 4, lc = lane & 15;
  const int m0   = blockIdx.x * 64;
  const int n0   = blockIdx.y * 128;
  const int wm = wv >> 1, wn = wv & 1;   // wave tile: 32 rows x 64 cols

  f32x4 acc[2][4] = {};

  for (int k0 = 0; k0 < DM; k0 += 32) {
    {
      const int e   = wv * 512 + lane * 8;
      const int row = e >> 5, col = e & 31;
      gload_lds16(Y + (size_t)(m0 + row) * DM + k0 + col, &As[wv * 512]);
    }
#pragma unroll
    for (int c = 0; c < 2; ++c) {
      const int e   = wv * 1024 + c * 512 + lane * 8;
      const int row = e >> 5, col = e & 31;
      gload_lds16(Wo + (size_t)(n0 + row) * DM + k0 + col, &Bs[wv * 1024 + c * 512]);
    }
    __syncthreads();
    bf16x8 a[2], b[4];
#pragma unroll
    for (int i = 0; i < 2; ++i)
      a[i] = *reinterpret_cast<const bf16x8*>(&As[(wm * 32 + i * 16 + lc) * 32 + lg * 8]);
#pragma unroll
    for (int j = 0; j < 4; ++j)
      b[j] = *reinterpret_cast<const bf16x8*>(&Bs[(wn * 64 + j * 16 + lc) * 32 + lg * 8]);
#pragma unroll
    for (int i = 0; i < 2; ++i)
#pragma unroll
      for (int j = 0; j < 4; ++j)
        acc[i][j] = __builtin_amdgcn_mfma_f32_16x16x32_bf16(a[i], b[j], acc[i][j], 0, 0, 0);
    __syncthreads();
  }

#pragma unroll
  for (int i = 0; i < 2; ++i) {
    const int mg = m0 + wm * 32 + i * 16 + lg * 4;
#pragma unroll
    for (int j = 0; j < 4; ++j) {
      const int n = n0 + wn * 64 + j * 16 + lc;
#pragma unroll
      for (int r = 0; r < 4; ++r)
        Out[(size_t)(mg + r) * DM + n] = acc[i][j][r];
    }
  }
}

extern "C" void kernel_launch(void* const* d_in, const int* in_sizes, int n_in,
                              void* d_out, int out_size, void* d_ws, size_t ws_size,
                              hipStream_t stream) {
  const float* x  = (const float*)d_in[0];
  const float* Wq = (const float*)d_in[1];
  const float* Wk = (const float*)d_in[2];
  const float* Wv = (const float*)d_in[3];
  const float* Wo = (const float*)d_in[4];
  float* out = (float*)d_out;
  char* ws = (char*)d_ws;
  const size_t MB = 1024 * 1024;

  bf16* xb  = (bf16*)(ws + 0);        // 8 MB, reused as yb after QKV GEMM
  bf16* wqb = (bf16*)(ws + 8  * MB);
  bf16* wkb = (bf16*)(ws + 10 * MB);
  bf16* wvb = (bf16*)(ws + 12 * MB);
  bf16* wob = (bf16*)(ws + 14 * MB);
  bf16* Qb  = (bf16*)(ws + 16 * MB);  // [32,2048,64]
  bf16* Kb  = (bf16*)(ws + 24 * MB);
  bf16* Vtb = (bf16*)(ws + 32 * MB);  // [32,64,2048]
  bf16* yb  = xb;

  cvt_all<<<8192, 256, 0, stream>>>(x, Wq, Wk, Wv, Wo, xb, wqb, wkb, wvb, wob);
  gemm_qkv<<<dim3(32, 24), 256, 0, stream>>>(xb, wqb, wkb, wvb, Qb, Kb, Vtb);
  attn_fwd<<<512, 256, 0, stream>>>(Qb, Kb, Vtb, yb);
  gemm_out<<<dim3(64, 8), 256, 0, stream>>>(yb, wob, out);
}

// Round 6
// 107.703 us; speedup vs baseline: 1.8222x; 1.0275x over previous
//
#include <hip/hip_runtime.h>
#include <hip/hip_bf16.h>
#include <stdint.h>

typedef __bf16 bf16;
typedef __bf16 bf16x8 __attribute__((ext_vector_type(8)));
typedef __bf16 bf16x4 __attribute__((ext_vector_type(4)));
typedef float  f32x4  __attribute__((ext_vector_type(4)));

#define DM 1024
#define NH 16
#define HD 64
#define TT 2048

// log2(e)/8 : puts QK^T scores directly in exp2 domain
#define QSCALE 0.18033688011112042f

__global__ void cvt_all(const float* __restrict__ x,  const float* __restrict__ wq,
                        const float* __restrict__ wk, const float* __restrict__ wv,
                        const float* __restrict__ wo,
                        bf16* __restrict__ xb,  bf16* __restrict__ wqb,
                        bf16* __restrict__ wkb, bf16* __restrict__ wvb,
                        bf16* __restrict__ wob) {
  const int i = (blockIdx.x * blockDim.x + threadIdx.x) * 4;
  const float* src; bf16* dst; int off;
  if (i < 4194304)      { src = x;  dst = xb;  off = i; }
  else {
    const int j = i - 4194304;
    const int w = j >> 20;
    off = j & 1048575;
    src = (w == 0) ? wq : (w == 1) ? wk : (w == 2) ? wv : wo;
    dst = (w == 0) ? wqb : (w == 1) ? wkb : (w == 2) ? wvb : wob;
  }
  const float4 v = *reinterpret_cast<const float4*>(src + off);
  bf16x4 o = { (bf16)v.x, (bf16)v.y, (bf16)v.z, (bf16)v.w };
  *reinterpret_cast<bf16x4*>(dst + off) = o;
}

static __device__ __forceinline__ void gload_lds16(const bf16* g, bf16* l) {
  __builtin_amdgcn_global_load_lds(
      (__attribute__((address_space(1))) void*)g,
      (__attribute__((address_space(3))) void*)l, 16, 0, 0);
}

// XOR swizzle: spreads the 8 16B-slots of a 128B row across banks by row
static __device__ __forceinline__ int swzb(int lin) {
  return lin ^ (((lin >> 7) & 7) << 4);
}

// ---------------- QKV projection (m97-style) ----------------
__launch_bounds__(256, 3)
__global__ void gemm_qkv(const bf16* __restrict__ X, const bf16* __restrict__ Wq,
                         const bf16* __restrict__ Wk, const bf16* __restrict__ Wv,
                         bf16* __restrict__ Qb, bf16* __restrict__ Kb,
                         bf16* __restrict__ Vtb) {
  __shared__ bf16 As[128 * 32];
  __shared__ bf16 Bs[128 * 32];
  const int tid  = threadIdx.x;
  const int lane = tid & 63;
  const int wv   = tid >> 6;
  const int lg   = lane >> 4, lc = lane & 15;
  const int m0   = blockIdx.x * 128;
  const int ng   = blockIdx.y * 128;
  const int which = ng >> 10;                 // 0=Q 1=K 2=V
  const bf16* W = (which == 0) ? Wq : ((which == 1) ? Wk : Wv);
  const int n0 = ng & 1023;
  const int wm = wv >> 1, wn = wv & 1;

  f32x4 acc[4][4] = {};

  for (int k0 = 0; k0 < DM; k0 += 32) {
#pragma unroll
    for (int c = 0; c < 2; ++c) {
      const int e   = wv * 512 + c * 2048 + lane * 8;
      const int row = e >> 5, col = e & 31;
      gload_lds16(X + (size_t)(m0 + row) * DM + k0 + col, &As[wv * 512 + c * 2048]);
      gload_lds16(W + (size_t)(n0 + row) * DM + k0 + col, &Bs[wv * 512 + c * 2048]);
    }
    __syncthreads();
    bf16x8 a[4], b[4];
#pragma unroll
    for (int i = 0; i < 4; ++i)
      a[i] = *reinterpret_cast<const bf16x8*>(&As[(wm * 64 + i * 16 + lc) * 32 + lg * 8]);
#pragma unroll
    for (int j = 0; j < 4; ++j)
      b[j] = *reinterpret_cast<const bf16x8*>(&Bs[(wn * 64 + j * 16 + lc) * 32 + lg * 8]);
#pragma unroll
    for (int i = 0; i < 4; ++i)
#pragma unroll
      for (int j = 0; j < 4; ++j)
        acc[i][j] = __builtin_amdgcn_mfma_f32_16x16x32_bf16(a[i], b[j], acc[i][j], 0, 0, 0);
    __syncthreads();
  }

#pragma unroll
  for (int i = 0; i < 4; ++i) {
    const int mg = m0 + wm * 64 + i * 16 + lg * 4;
    const int bb = mg >> 11, t = mg & 2047;
#pragma unroll
    for (int j = 0; j < 4; ++j) {
      const int nl = n0 + wn * 64 + j * 16 + lc;
      const int h = nl >> 6, d = nl & 63;
      const int bh = bb * NH + h;
      const f32x4 v = acc[i][j];
      if (which == 0) {
        bf16* p = Qb + ((size_t)bh * TT + t) * HD + d;
#pragma unroll
        for (int r = 0; r < 4; ++r) p[r * HD] = (bf16)(v[r] * QSCALE);
      } else if (which == 1) {
        bf16* p = Kb + ((size_t)bh * TT + t) * HD + d;
#pragma unroll
        for (int r = 0; r < 4; ++r) p[r * HD] = (bf16)v[r];
      } else {
        bf16x4 pk = { (bf16)v[0], (bf16)v[1], (bf16)v[2], (bf16)v[3] };
        *reinterpret_cast<bf16x4*>(Vtb + ((size_t)bh * HD + d) * TT + t) = pk;
      }
    }
  }
}

// ---------------- flash attention ----------------
// 1024 blocks: bh = bid&31, qblk = 31-(bid>>5) (heavy-first for dynamic
// balance). One 64-row q-block per block, qblk+1 kv-tiles. 4 waves x 16
// q-rows, 3 blocks/CU. Counted-vmcnt 2-phase pipeline; XOR-swizzled K/V;
// swapped QK^T; O^T accumulation; l-sum reduction moved after PV.
#define KPAD 72

__launch_bounds__(256, 3)
__global__ void attn_fwd(const bf16* __restrict__ Qb, const bf16* __restrict__ Kb,
                         const bf16* __restrict__ Vtb, bf16* __restrict__ Yb) {
  __shared__ bf16 Ks[2][4096];     // [buf][64 kv x 64 d] swizzled
  __shared__ bf16 Vs[2][4096];     // [buf][64 d x 64 kv] swizzled
  __shared__ bf16 Ps[4][16 * KPAD];

  const int tid  = threadIdx.x;
  const int lane = tid & 63;
  const int wv   = tid >> 6;       // 0..3
  const int lg   = lane >> 4;
  const int lc   = lane & 15;
  const int bh   = blockIdx.x & 31;
  const int qblk = 31 - (blockIdx.x >> 5);   // heavy blocks dispatch first
  const int q0   = qblk * 64;
  const int NT   = qblk + 1;

  const bf16* Qg = Qb  + (size_t)bh * TT * HD;
  const bf16* Kg = Kb  + (size_t)bh * TT * HD;
  const bf16* Vg = Vtb + (size_t)bh * HD * TT;

  // Q fragments (B-operand; pre-scaled by QSCALE)
  const bf16x8 qf0 = *reinterpret_cast<const bf16x8*>(
      Qg + (size_t)(q0 + wv * 16 + lc) * HD + 0  + lg * 8);
  const bf16x8 qf1 = *reinterpret_cast<const bf16x8*>(
      Qg + (size_t)(q0 + wv * 16 + lc) * HD + 32 + lg * 8);

  // staging offsets: dest linear (wave-uniform base + lane*16), src pre-swizzled
  int dstb[2], koff[2], voff[2];
#pragma unroll
  for (int c = 0; c < 2; ++c) {
    const int base = (wv * 2 + c) * 1024;        // byte base of this issue
    const int lin  = base + lane * 16;
    dstb[c] = base;
    koff[c] = swzb(lin);
    voff[c] = (lin >> 7) * (TT * 2) + (swzb(lin) & 127);
  }

  auto STAGE = [&](int b, int kv) {
#pragma unroll
    for (int c = 0; c < 2; ++c) {
      gload_lds16((const bf16*)((const char*)Kg + (size_t)kv * 8192 + koff[c]),
                  (bf16*)((char*)Ks[b] + dstb[c]));
      gload_lds16((const bf16*)((const char*)Vg + (size_t)kv * 128 + voff[c]),
                  (bf16*)((char*)Vs[b] + dstb[c]));
    }
  };

  f32x4 o[4] = {};                 // O^T: o[df] row d = df*16+lg*4+r, col q = lc
  float m_run = -INFINITY, l_run = 0.f;
  bf16* Pw = Ps[wv];
  const int b_ = bh >> 4, h_ = bh & 15;
  const int qw = q0 + wv * 16;

  STAGE(0, 0);                     // 4 loads outstanding

  int cur = 0;
  for (int ti = 0; ti < NT; ++ti) {
    const int k0 = ti * 64;

    // prefetch next tile, then wait only for the CURRENT tile's 4 loads
    if (ti + 1 < NT) {
      STAGE(cur ^ 1, ti + 1);
      asm volatile("s_waitcnt vmcnt(4)" ::: "memory");
    } else {
      asm volatile("s_waitcnt vmcnt(0)" ::: "memory");
    }
    __builtin_amdgcn_s_barrier();          // all waves' current-tile loads landed
    __builtin_amdgcn_sched_barrier(0);

    const char* ksb = (const char*)Ks[cur];
    const char* vsb = (const char*)Vs[cur];

    // S^T = K Q^T : s[kvf], lane holds kv = k0+kvf*16+lg*4+r, q = q0+wv*16+lc
    f32x4 s[4] = {};
    __builtin_amdgcn_s_setprio(1);
#pragma unroll
    for (int kvf = 0; kvf < 4; ++kvf) {
      const bf16x8 k0f = *reinterpret_cast<const bf16x8*>(
          ksb + swzb((kvf * 16 + lc) * 128 + lg * 16));
      s[kvf] = __builtin_amdgcn_mfma_f32_16x16x32_bf16(k0f, qf0, s[kvf], 0, 0, 0);
      const bf16x8 k1f = *reinterpret_cast<const bf16x8*>(
          ksb + swzb((kvf * 16 + lc) * 128 + 64 + lg * 16));
      s[kvf] = __builtin_amdgcn_mfma_f32_16x16x32_bf16(k1f, qf1, s[kvf], 0, 0, 0);
    }
    __builtin_amdgcn_s_setprio(0);

    // causal mask (true only on the final/diagonal tile)
    if (k0 + 63 > qw) {
      const int q = qw + lc;
#pragma unroll
      for (int kvf = 0; kvf < 4; ++kvf)
#pragma unroll
        for (int r = 0; r < 4; ++r)
          if (k0 + kvf * 16 + lg * 4 + r > q) s[kvf][r] = -INFINITY;
    }

    // online softmax max-phase (exp2 domain); stats live in q = lc layout
    float t0 = fmaxf(fmaxf(s[0][0], s[0][1]), fmaxf(s[0][2], s[0][3]));
    float t1 = fmaxf(fmaxf(s[1][0], s[1][1]), fmaxf(s[1][2], s[1][3]));
    float t2 = fmaxf(fmaxf(s[2][0], s[2][1]), fmaxf(s[2][2], s[2][3]));
    float t3 = fmaxf(fmaxf(s[3][0], s[3][1]), fmaxf(s[3][2], s[3][3]));
    float rmax = fmaxf(fmaxf(t0, t1), fmaxf(t2, t3));
    rmax = fmaxf(rmax, __shfl_xor(rmax, 16));
    rmax = fmaxf(rmax, __shfl_xor(rmax, 32));

    const float mn = fmaxf(m_run, rmax);
    const float alpha = __builtin_amdgcn_exp2f(m_run - mn);
    m_run = mn;

#pragma unroll
    for (int kvf = 0; kvf < 4; ++kvf)
#pragma unroll
      for (int r = 0; r < 4; ++r)
        s[kvf][r] = __builtin_amdgcn_exp2f(s[kvf][r] - mn);

    // rescale O^T: col q = lc -> alpha applies uniformly per lane (no shfl)
#pragma unroll
    for (int df = 0; df < 4; ++df)
#pragma unroll
      for (int r = 0; r < 4; ++r) o[df][r] *= alpha;

    // P -> per-wave LDS: row q=lc, col kv (for B-operand re-read)
#pragma unroll
    for (int kvf = 0; kvf < 4; ++kvf) {
      bf16x4 pk = { (bf16)s[kvf][0], (bf16)s[kvf][1],
                    (bf16)s[kvf][2], (bf16)s[kvf][3] };
      *reinterpret_cast<bf16x4*>(&Pw[lc * KPAD + kvf * 16 + lg * 4]) = pk;
    }

    // O^T += V^T P : A = V^T frag (row d=..+lc), B = P frag (col q=lc)
    __builtin_amdgcn_s_setprio(1);
#pragma unroll
    for (int ks = 0; ks < 2; ++ks) {
      const bf16x8 pf = *reinterpret_cast<const bf16x8*>(
          &Pw[lc * KPAD + ks * 32 + lg * 8]);
#pragma unroll
      for (int df = 0; df < 4; ++df) {
        const bf16x8 vf = *reinterpret_cast<const bf16x8*>(
            vsb + swzb((df * 16 + lc) * 128 + ks * 64 + lg * 16));
        o[df] = __builtin_amdgcn_mfma_f32_16x16x32_bf16(vf, pf, o[df], 0, 0, 0);
      }
    }
    __builtin_amdgcn_s_setprio(0);

    // l-sum reduction AFTER PV issue: off the pre-PV critical chain
    float u0 = (s[0][0] + s[0][1]) + (s[0][2] + s[0][3]);
    float u1 = (s[1][0] + s[1][1]) + (s[1][2] + s[1][3]);
    float u2 = (s[2][0] + s[2][1]) + (s[2][2] + s[2][3]);
    float u3 = (s[3][0] + s[3][1]) + (s[3][2] + s[3][3]);
    float rsum = (u0 + u1) + (u2 + u3);
    rsum += __shfl_xor(rsum, 16);
    rsum += __shfl_xor(rsum, 32);
    l_run = l_run * alpha + rsum;

    __builtin_amdgcn_s_barrier();    // all waves done reading buffer `cur`
    cur ^= 1;
  }

  // writeback
  {
    const float linv = 1.f / fmaxf(l_run, 1e-9f);
    const int q = qw + lc;
#pragma unroll
    for (int df = 0; df < 4; ++df) {
      bf16x4 yv = { (bf16)(o[df][0] * linv), (bf16)(o[df][1] * linv),
                    (bf16)(o[df][2] * linv), (bf16)(o[df][3] * linv) };
      *reinterpret_cast<bf16x4*>(
          Yb + ((size_t)(b_ * TT + q)) * DM + h_ * HD + df * 16 + lg * 4) = yv;
    }
  }
}

// ---------------- output projection (64x128 tiles, 512 blocks = 2/CU) -------
__launch_bounds__(256, 2)
__global__ void gemm_out(const bf16* __restrict__ Y, const bf16* __restrict__ Wo,
                         float* __restrict__ Out) {
  __shared__ bf16 As[64 * 32];
  __shared__ bf16 Bs[128 * 32];
  const int tid  = threadIdx.x;
  const int lane = tid & 63;
  const int wv   = tid >> 6;
  const int lg   = lane >> 4, lc = lane & 15;
  const int m0   = blockIdx.x * 64;
  const int n0   = blockIdx.y * 128;
  const int wm = wv >> 1, wn = wv & 1;   // wave tile: 32 rows x 64 cols

  f32x4 acc[2][4] = {};

  for (int k0 = 0; k0 < DM; k0 += 32) {
    {
      const int e   = wv * 512 + lane * 8;
      const int row = e >> 5, col = e & 31;
      gload_lds16(Y + (size_t)(m0 + row) * DM + k0 + col, &As[wv * 512]);
    }
#pragma unroll
    for (int c = 0; c < 2; ++c) {
      const int e   = wv * 1024 + c * 512 + lane * 8;
      const int row = e >> 5, col = e & 31;
      gload_lds16(Wo + (size_t)(n0 + row) * DM + k0 + col, &Bs[wv * 1024 + c * 512]);
    }
    __syncthreads();
    bf16x8 a[2], b[4];
#pragma unroll
    for (int i = 0; i < 2; ++i)
      a[i] = *reinterpret_cast<const bf16x8*>(&As[(wm * 32 + i * 16 + lc) * 32 + lg * 8]);
#pragma unroll
    for (int j = 0; j < 4; ++j)
      b[j] = *reinterpret_cast<const bf16x8*>(&Bs[(wn * 64 + j * 16 + lc) * 32 + lg * 8]);
#pragma unroll
    for (int i = 0; i < 2; ++i)
#pragma unroll
      for (int j = 0; j < 4; ++j)
        acc[i][j] = __builtin_amdgcn_mfma_f32_16x16x32_bf16(a[i], b[j], acc[i][j], 0, 0, 0);
    __syncthreads();
  }

#pragma unroll
  for (int i = 0; i < 2; ++i) {
    const int mg = m0 + wm * 32 + i * 16 + lg * 4;
#pragma unroll
    for (int j = 0; j < 4; ++j) {
      const int n = n0 + wn * 64 + j * 16 + lc;
#pragma unroll
      for (int r = 0; r < 4; ++r)
        Out[(size_t)(mg + r) * DM + n] = acc[i][j][r];
    }
  }
}

extern "C" void kernel_launch(void* const* d_in, const int* in_sizes, int n_in,
                              void* d_out, int out_size, void* d_ws, size_t ws_size,
                              hipStream_t stream) {
  const float* x  = (const float*)d_in[0];
  const float* Wq = (const float*)d_in[1];
  const float* Wk = (const float*)d_in[2];
  const float* Wv = (const float*)d_in[3];
  const float* Wo = (const float*)d_in[4];
  float* out = (float*)d_out;
  char* ws = (char*)d_ws;
  const size_t MB = 1024 * 1024;

  bf16* xb  = (bf16*)(ws + 0);        // 8 MB, reused as yb after QKV GEMM
  bf16* wqb = (bf16*)(ws + 8  * MB);
  bf16* wkb = (bf16*)(ws + 10 * MB);
  bf16* wvb = (bf16*)(ws + 12 * MB);
  bf16* wob = (bf16*)(ws + 14 * MB);
  bf16* Qb  = (bf16*)(ws + 16 * MB);  // [32,2048,64]
  bf16* Kb  = (bf16*)(ws + 24 * MB);
  bf16* Vtb = (bf16*)(ws + 32 * MB);  // [32,64,2048]
  bf16* yb  = xb;

  cvt_all<<<8192, 256, 0, stream>>>(x, Wq, Wk, Wv, Wo, xb, wqb, wkb, wvb, wob);
  gemm_qkv<<<dim3(32, 24), 256, 0, stream>>>(xb, wqb, wkb, wvb, Qb, Kb, Vtb);
  attn_fwd<<<1024, 256, 0, stream>>>(Qb, Kb, Vtb, yb);
  gemm_out<<<dim3(64, 8), 256, 0, stream>>>(yb, wob, out);
}